// Round 14
// baseline (2571.297 us; speedup 1.0000x reference)
//
#include <hip/hip_runtime.h>
#include <hip/hip_fp16.h>
#include <cmath>

// Problem constants (reference: B=256, T=512, IN=64, R=2048)
constexpr int kB  = 256;
constexpr int kT  = 512;
constexpr int kIN = 64;
constexpr int kR  = 2048;

constexpr int kBands  = 8;             // m-bands; band = blockIdx&7 -> XCD-local under
                                       // round-robin dispatch (r9/r12-verified)
constexpr int kNB     = 32;            // n-blocks per band
constexpr int kBlocks = kBands * kNB;  // 256 -> 1 block/CU (r10: 2/CU regresses)
constexpr int BM = 32;                 // batches per block
constexpr int BN = 64;                 // n per block (W-band in registers, nh-split)
constexpr int CH  = 1024;              // k per staged s-chunk (= 16 producer blocks)
constexpr int NCH = kR / CH;           // 2 chunks
constexpr int SST = CH + 8;            // ss row stride (halfs) = 1032
constexpr int PFS = 68;                // partial-scratch row stride (words)

typedef _Float16 f16x8 __attribute__((ext_vector_type(8)));
typedef float    f32x4 __attribute__((ext_vector_type(4)));
typedef unsigned long long u64;

#define MFMA16(a, b, c) __builtin_amdgcn_mfma_f32_16x16x32_f16((a), (b), (c), 0, 0, 0)

__device__ __forceinline__ f16x8 cvt8(float4 a, float4 b) {
    f16x8 v;
    v[0] = (_Float16)a.x; v[1] = (_Float16)a.y; v[2] = (_Float16)a.z; v[3] = (_Float16)a.w;
    v[4] = (_Float16)b.x; v[5] = (_Float16)b.y; v[6] = (_Float16)b.z; v[7] = (_Float16)b.w;
    return v;
}

__device__ __forceinline__ unsigned get_xcc_id() {
    unsigned x;
    asm volatile("s_getreg_b32 %0, hwreg(HW_REG_XCC_ID, 0, 8)" : "=s"(x));
    return x & 0xfu;
}

// One coalesced poll of the band's 32 per-block flags (agent-scope).
__device__ __forceinline__ unsigned poll32(const unsigned* f, int lane, unsigned target) {
    unsigned v = __hip_atomic_load(f + (lane & 31), __ATOMIC_RELAXED, __HIP_MEMORY_SCOPE_AGENT);
    return (unsigned)__ballot(v >= target);
}
// Chunk pc (1024 k) is produced by band-blocks [16*pc, 16*pc+16).
__device__ __forceinline__ bool chunk_ready16(unsigned fm, int pc) {
    return ((fm >> (16 * pc)) & 0xffffu) == 0xffffu;
}

// Persistent ESN, r14 = r12 coherence (verified XCD fast path, 2.43 ms) with a
// restructured K-loop: NCH=2 x CH=1024, all staging loads issued at the step
// head (16 x 16B/thread in flight after one detect), chunk-1's flight overlaps
// chunk-0's compute; barriers 8 -> 5 per step; fp32 partial scratch aliases
// ss[0] (time-disjoint). r13's L2-local flags were neutral -> reverted.
__global__ __launch_bounds__(512, 2) void esn_persist(
    const float* __restrict__ X,     // [B, T, IN]
    const float* __restrict__ Win,   // [R, IN]
    const float* __restrict__ W,     // [R, R]
    float* __restrict__ out,         // [B, R]
    _Float16* __restrict__ sbuf0,
    _Float16* __restrict__ sbuf1,
    unsigned* __restrict__ flags,    // [8][32], zeroed at launch
    unsigned* __restrict__ xcds)     // [8][32], zeroed at launch
{
    // ssA/ssB: 2 x 32 x 1032 halfs = 2 x 66048 B = 132096 B.
    // pf (4 x 32 x 68 fp32 = 34816 B) aliases ssA: written only after both
    // chunk computes; next step's ssA writes are behind the epilogue barrier.
    __shared__ __align__(16) char smem[2 * BM * SST * 2];
    _Float16* ssA = (_Float16*)smem;
    _Float16* ssB = (_Float16*)(smem + BM * SST * 2);
    float*    pf  = (float*)smem;
    __shared__ unsigned fm_sh;
    __shared__ int fast_sh;

    const int tid  = threadIdx.x;
    const int wave = tid >> 6, lane = tid & 63;
    const int quad = lane >> 4, l16 = lane & 15;
    const int nh = wave >> 2;        // n-half: cols [nh*32, nh*32+32)
    const int q  = wave & 3;         // k-phase: window ≡ q (mod 4)
    const int mb = blockIdx.x & 7;   // band (XCD-local heuristic, HW-verified)
    const int nb = blockIdx.x >> 3;  // n-block within band
    const int n0 = nb * BN;
    const int m0 = mb * BM;
    const int c0 = nb >> 4;          // own chunk / ring start (0..1)
    unsigned* bandflags = flags + mb * kNB;
    unsigned* bandxcc   = xcds  + mb * kNB;

    if (tid == 0) {
        fast_sh = 0;
        __hip_atomic_store(&bandxcc[nb], get_xcc_id() + 1u,
                           __ATOMIC_RELAXED, __HIP_MEMORY_SCOPE_AGENT);
    }

    // ---- one-time: W-band -> register B-frags (f16), ring-permuted ----
    // Ring pos c (0/1) -> physical chunk p(c) = (c0+c)&1 (32 k-windows each;
    // phase q owns windows 4j+q, j=0..7).
    // wfrag[h][8c+j] = W[n0+nh*32+h*16+l16][kk*32+quad*8+..], kk = p(c)*32+4j+q
    f16x8 wfrag[2][8 * NCH];
    #pragma unroll
    for (int h = 0; h < 2; ++h) {
        const float* wrow = W + (size_t)(n0 + nh * 32 + h * 16 + l16) * kR;
        #pragma unroll
        for (int kki = 0; kki < 8 * NCH; ++kki) {
            const int kk = (((c0 + (kki >> 3)) & 1) << 5) + (kki & 7) * 4 + q;
            const float* p = wrow + kk * 32 + quad * 8;
            wfrag[h][kki] = cvt8(*(const float4*)p, *(const float4*)(p + 4));
        }
    }
    f16x8 winfrag[2] = {};
    if (q < 2) {
        #pragma unroll
        for (int h = 0; h < 2; ++h) {
            const float* p = Win + (size_t)(n0 + nh * 32 + h * 16 + l16) * kIN
                           + q * 32 + quad * 8;
            winfrag[h] = cvt8(*(const float4*)p, *(const float4*)(p + 4));
        }
    }

    // s staging geometry: thread -> row tid>>4 (0..31), 8 x 16B units per
    // chunk at halfs col (tid&15)*8 + u*128. Coalesced 256-B runs.
    const int srow = tid >> 4;
    const int sc8  = (tid & 15) * 8;                 // halfs
    const size_t sgbase = (size_t)(m0 + srow) * kR + sc8;
    const int ldst = srow * SST + sc8;               // LDS halfs offset

    unsigned fastw = 0;   // wave0's register copy of the fast-path predicate

    #pragma unroll 1
    for (int t = 0; t < kT; ++t) {
        // ---- X-frag raw loads for THIS step (latency hidden under sync) ----
        float4 xr[2][2];
        if (q < 2) {
            #pragma unroll
            for (int i = 0; i < 2; ++i) {
                const float* xp = X + ((size_t)(m0 + i * 16 + l16) * kT + t) * kIN
                                + q * 32 + quad * 8;
                xr[i][0] = *(const float4*)xp;
                xr[i][1] = *(const float4*)(xp + 4);
            }
        }

        f32x4 acc[2][2] = {};   // [m-tile][n-tile within n-half]

        // ---- recurrent term over s_{t-1}: 2 chunks, head-issued loads ----
        if (t > 0) {
            const _Float16* sprev = (t & 1) ? sbuf0 : sbuf1;
            const unsigned target = (unsigned)t;   // flag >= t <=> s[t-1] published

            if (wave == 0) {
                if (t == 1) {
                    // one-time: wait for the WHOLE band, then verify XCD
                    // co-location (xcds visible once flags >= 1).
                    unsigned fm = poll32(bandflags, lane, target);
                    while (fm != 0xffffffffu) {
                        __builtin_amdgcn_s_sleep(1);
                        fm = poll32(bandflags, lane, target);
                    }
                    const unsigned myx = get_xcc_id() + 1u;
                    unsigned px = __hip_atomic_load(bandxcc + (lane & 31),
                                                    __ATOMIC_RELAXED,
                                                    __HIP_MEMORY_SCOPE_AGENT);
                    const bool same = (__ballot(px == myx) == ~0ull);
                    fastw = same ? 1u : 0u;
                    if (lane == 0) { fast_sh = (int)fastw; fm_sh = fm; }
                } else {
                    unsigned fm = poll32(bandflags, lane, target);
                    while (!chunk_ready16(fm, c0)) {
                        __builtin_amdgcn_s_sleep(1);
                        fm = poll32(bandflags, lane, target);
                    }
                    if (lane == 0) fm_sh = fm;
                }
                if (fastw && t >= 2) {
                    // fast: L1-only invalidate (per-CU, parallel); s lives in
                    // this XCD's shared L2, updated directly by peers' stores.
                    asm volatile("buffer_inv sc0" ::: "memory");
                } else {
                    // safe: full agent acquire (L1+L2 invalidate)
                    __builtin_amdgcn_fence(__ATOMIC_ACQUIRE, "agent");
                }
            }
            __syncthreads();                       // barrier 1 (detect/inv)
            unsigned fmask = fm_sh;
            asm volatile("" ::: "memory");

            const int pc1 = c0 ^ 1;
            const size_t offA = (size_t)c0  * CH;
            const size_t offB = (size_t)pc1 * CH;

            f16x8 rga[8], rgb[8];
            // chunk ring-0 (own, confirmed): issue all 8 loads
            #pragma unroll
            for (int u = 0; u < 8; ++u)
                rga[u] = *(const f16x8*)(sprev + sgbase + offA + u * 128);
            // chunk ring-1: issue immediately if already published (steady state)
            bool c1issued = chunk_ready16(fmask, pc1);
            if (c1issued) {
                #pragma unroll
                for (int u = 0; u < 8; ++u)
                    rgb[u] = *(const f16x8*)(sprev + sgbase + offB + u * 128);
            }
            // stage chunk ring-0
            #pragma unroll
            for (int u = 0; u < 8; ++u)
                *(f16x8*)&ssA[ldst + u * 128] = rga[u];
            __syncthreads();                       // barrier 2 (stage0)

            // compute ring-0 (chunk-1's loads still in flight)
            #pragma unroll
            for (int j = 0; j < 8; ++j) {
                const int kloc = (4 * j + q) * 32 + quad * 8;
                f16x8 av0 = *(const f16x8*)&ssA[(l16) * SST + kloc];
                f16x8 av1 = *(const f16x8*)&ssA[(16 + l16) * SST + kloc];
                acc[0][0] = MFMA16(av0, wfrag[0][j], acc[0][0]);
                acc[0][1] = MFMA16(av0, wfrag[1][j], acc[0][1]);
                acc[1][0] = MFMA16(av1, wfrag[0][j], acc[1][0]);
                acc[1][1] = MFMA16(av1, wfrag[1][j], acc[1][1]);
            }

            if (!c1issued) {   // rare: straggler producers for the other chunk
                unsigned fm = poll32(bandflags, lane, target);
                while (!chunk_ready16(fm, pc1)) {
                    __builtin_amdgcn_s_sleep(1);
                    fm = poll32(bandflags, lane, target);
                }
                asm volatile("" ::: "memory");
                #pragma unroll
                for (int u = 0; u < 8; ++u)
                    rgb[u] = *(const f16x8*)(sprev + sgbase + offB + u * 128);
            }
            // stage chunk ring-1
            #pragma unroll
            for (int u = 0; u < 8; ++u)
                *(f16x8*)&ssB[ldst + u * 128] = rgb[u];
            __syncthreads();                       // barrier 3 (stage1)

            // compute ring-1
            #pragma unroll
            for (int j = 0; j < 8; ++j) {
                const int kloc = (4 * j + q) * 32 + quad * 8;
                f16x8 av0 = *(const f16x8*)&ssB[(l16) * SST + kloc];
                f16x8 av1 = *(const f16x8*)&ssB[(16 + l16) * SST + kloc];
                acc[0][0] = MFMA16(av0, wfrag[0][8 + j], acc[0][0]);
                acc[0][1] = MFMA16(av0, wfrag[1][8 + j], acc[0][1]);
                acc[1][0] = MFMA16(av1, wfrag[0][8 + j], acc[1][0]);
                acc[1][1] = MFMA16(av1, wfrag[1][8 + j], acc[1][1]);
            }
        }

        // ---- input term (X loads long done) ----
        if (q < 2) {
            #pragma unroll
            for (int i = 0; i < 2; ++i) {
                f16x8 a = cvt8(xr[i][0], xr[i][1]);
                acc[i][0] = MFMA16(a, winfrag[0], acc[i][0]);
                acc[i][1] = MFMA16(a, winfrag[1], acc[i][1]);
            }
        }

        // ---- reduce 4 k-phase partials through LDS (aliases ssA), tanh ----
        #pragma unroll
        for (int i = 0; i < 2; ++i)
            #pragma unroll
            for (int h = 0; h < 2; ++h)
                #pragma unroll
                for (int r = 0; r < 4; ++r)
                    pf[q * BM * PFS + (i * 16 + quad * 4 + r) * PFS + nh * 32 + h * 16 + l16]
                        = acc[i][h][r];
        __syncthreads();                           // barrier 4 (pf)

        // thread -> (m = tid>>4, 4 n at (tid&15)*4)
        const int ml = tid >> 4, nl4 = (tid & 15) * 4;
        f32x4 v0 = *(const f32x4*)&pf[0 * BM * PFS + ml * PFS + nl4];
        f32x4 v1 = *(const f32x4*)&pf[1 * BM * PFS + ml * PFS + nl4];
        f32x4 v2 = *(const f32x4*)&pf[2 * BM * PFS + ml * PFS + nl4];
        f32x4 v3 = *(const f32x4*)&pf[3 * BM * PFS + ml * PFS + nl4];
        float o0 = tanhf(v0[0] + v1[0] + v2[0] + v3[0]);
        float o1 = tanhf(v0[1] + v1[1] + v2[1] + v3[1]);
        float o2 = tanhf(v0[2] + v1[2] + v2[2] + v3[2]);
        float o3 = tanhf(v0[3] + v1[3] + v2[3] + v3[3]);

        if (t < kT - 1) {
            _Float16* sout = (t & 1) ? sbuf1 : sbuf0;
            union { u64 u; _Float16 h[4]; } pk;
            pk.h[0] = (_Float16)o0; pk.h[1] = (_Float16)o1;
            pk.h[2] = (_Float16)o2; pk.h[3] = (_Float16)o3;
            u64* dst = (u64*)(sout + (size_t)(m0 + ml) * kR + n0 + nl4);
            if (fast_sh) {
                *dst = pk.u;                     // write-back: lands in the
                asm volatile("" ::: "memory");   // XCD's shared L2 (verified)
            } else {
                __hip_atomic_store(dst, pk.u, __ATOMIC_RELAXED,
                                   __HIP_MEMORY_SCOPE_AGENT);  // through to L3
            }
            __builtin_amdgcn_s_waitcnt(0);   // store (and xcc publish) completed
            __syncthreads();                 // barrier 5 (drain; guards pf/ssA)
            if (tid == 0)
                __hip_atomic_store(&bandflags[nb], (unsigned)(t + 1),
                                   __ATOMIC_RELAXED, __HIP_MEMORY_SCOPE_AGENT);
        } else {
            float4 o; o.x = o0; o.y = o1; o.z = o2; o.w = o3;
            *(float4*)(out + (size_t)(m0 + ml) * kR + n0 + nl4) = o;
        }
    }
}

extern "C" void kernel_launch(void* const* d_in, const int* in_sizes, int n_in,
                              void* d_out, int out_size, void* d_ws, size_t ws_size,
                              hipStream_t stream)
{
    const float* X   = (const float*)d_in[0];  // [B, T, IN]
    const float* Win = (const float*)d_in[1];  // [R, IN]
    const float* W   = (const float*)d_in[2];  // [R, R]
    float* out = (float*)d_out;                // [B, R]

    char* ws = (char*)d_ws;
    _Float16* s0 = (_Float16*)ws;                                  // 1 MB
    _Float16* s1 = (_Float16*)(ws + (size_t)kB * kR * 2);          // 1 MB
    unsigned* flags = (unsigned*)(ws + 2 * (size_t)kB * kR * 2);   // [8][32]
    unsigned* xcds  = flags + kBands * kNB;                        // [8][32]

    hipMemsetAsync(flags, 0, 2 * kBands * kNB * sizeof(unsigned), stream);
    esn_persist<<<kBlocks, 512, 0, stream>>>(X, Win, W, out, s0, s1, flags, xcds);
}

// Round 15
// 2176.402 us; speedup vs baseline: 1.1814x; 1.1814x over previous
//
#include <hip/hip_runtime.h>
#include <hip/hip_fp16.h>
#include <cmath>

// Problem constants (reference: B=256, T=512, IN=64, R=2048)
constexpr int kB  = 256;
constexpr int kT  = 512;
constexpr int kIN = 64;
constexpr int kR  = 2048;

constexpr int kBands  = 8;             // m-bands; band = blockIdx&7 -> XCD-local under
                                       // round-robin dispatch (r9/r12-verified)
constexpr int kNB     = 32;            // n-blocks per band
constexpr int kBlocks = kBands * kNB;  // 256 -> 1 block/CU (r10: 2/CU regresses)
constexpr int BM = 32;                 // batches per block
constexpr int BN = 64;                 // n per block (W-band in registers, nh-split)
constexpr int PFS = 68;                // partial-scratch row stride (words)

typedef _Float16 f16x8 __attribute__((ext_vector_type(8)));
typedef float    f32x4 __attribute__((ext_vector_type(4)));
typedef unsigned long long u64;

#define MFMA16(a, b, c) __builtin_amdgcn_mfma_f32_16x16x32_f16((a), (b), (c), 0, 0, 0)

__device__ __forceinline__ f16x8 cvt8(float4 a, float4 b) {
    f16x8 v;
    v[0] = (_Float16)a.x; v[1] = (_Float16)a.y; v[2] = (_Float16)a.z; v[3] = (_Float16)a.w;
    v[4] = (_Float16)b.x; v[5] = (_Float16)b.y; v[6] = (_Float16)b.z; v[7] = (_Float16)b.w;
    return v;
}

__device__ __forceinline__ unsigned get_xcc_id() {
    unsigned x;
    asm volatile("s_getreg_b32 %0, hwreg(HW_REG_XCC_ID, 0, 8)" : "=s"(x));
    return x & 0xfu;
}

// One coalesced poll of the band's 32 per-block flags (agent-scope).
__device__ __forceinline__ unsigned poll32(const unsigned* f, int lane, unsigned target) {
    unsigned v = __hip_atomic_load(f + (lane & 31), __ATOMIC_RELAXED, __HIP_MEMORY_SCOPE_AGENT);
    return (unsigned)__ballot(v >= target);
}

// Persistent ESN, r15 = r12 coherence (verified XCD fast path) + SWIZZLED s
// exchange: s[t] is stored in MFMA-A-fragment order
//   s_swz[mb][mt][kw][quad][l16][8]   (mt = m-tile/16, kw = k-window/32)
// so a consumer wave's A-fragment load is 64 lanes x 16 B CONTIGUOUS (1 KB)
// straight from global (L2) — no LDS staging at all (r7's gather problem is
// fixed at the producer). Producer epilogue writes are contiguous u64 per
// thread. Deletes ss LDS traffic + 2 barriers (5 -> 3/step) + most bank
// conflicts. Detect = one whole-band wait (steady state always ready, r14).
// Fragment loads pipeline in 4 groups of 8 frags, double-buffered (vmcnt MLP).
__global__ __launch_bounds__(512, 2) void esn_persist(
    const float* __restrict__ X,     // [B, T, IN]
    const float* __restrict__ Win,   // [R, IN]
    const float* __restrict__ W,     // [R, R]
    float* __restrict__ out,         // [B, R]
    _Float16* __restrict__ sbuf0,    // swizzled, 1 MB
    _Float16* __restrict__ sbuf1,    // swizzled, 1 MB
    unsigned* __restrict__ flags,    // [8][32], zeroed at launch
    unsigned* __restrict__ xcds)     // [8][32], zeroed at launch
{
    __shared__ __align__(16) float pf[4 * BM * PFS];     // 34816 B
    __shared__ int fast_sh;

    const int tid  = threadIdx.x;
    const int wave = tid >> 6, lane = tid & 63;
    const int quad = lane >> 4, l16 = lane & 15;
    const int nh = wave >> 2;        // n-half: cols [nh*32, nh*32+32)
    const int q  = wave & 3;         // k-phase: kw ≡ q (mod 4)
    const int mb = blockIdx.x & 7;   // band (XCD-local heuristic, HW-verified)
    const int nb = blockIdx.x >> 3;  // n-block within band
    const int n0 = nb * BN;
    const int m0 = mb * BM;
    unsigned* bandflags = flags + mb * kNB;
    unsigned* bandxcc   = xcds  + mb * kNB;

    if (tid == 0) {
        fast_sh = 0;
        __hip_atomic_store(&bandxcc[nb], get_xcc_id() + 1u,
                           __ATOMIC_RELAXED, __HIP_MEMORY_SCOPE_AGENT);
    }

    // ---- one-time: W-band -> register B-frags (f16), straight k order ----
    // wfrag[h][j] = W[n0+nh*32+h*16+l16][kk*32+quad*8+..], kk = 4j+q, j=0..15
    f16x8 wfrag[2][16];
    #pragma unroll
    for (int h = 0; h < 2; ++h) {
        const float* wrow = W + (size_t)(n0 + nh * 32 + h * 16 + l16) * kR;
        #pragma unroll
        for (int j = 0; j < 16; ++j) {
            const float* p = wrow + (4 * j + q) * 32 + quad * 8;
            wfrag[h][j] = cvt8(*(const float4*)p, *(const float4*)(p + 4));
        }
    }
    f16x8 winfrag[2] = {};
    if (q < 2) {
        #pragma unroll
        for (int h = 0; h < 2; ++h) {
            const float* p = Win + (size_t)(n0 + nh * 32 + h * 16 + l16) * kIN
                           + q * 32 + quad * 8;
            winfrag[h] = cvt8(*(const float4*)p, *(const float4*)(p + 4));
        }
    }

    // Consumer fragment geometry: frag (mt, j) at halfs offset
    //   fbase + mt*32768 + j*2048, fbase = (mb*2)*64*512 + (4*0+q)? ->
    //   addr(mb,mt,kw,quad,l16) = (((mb*2+mt)*64 + kw)*4 + quad)*16*8 + l16*8,
    //   kw = 4j+q  =>  j stride = 4*512 = 2048 halfs, mt stride = 64*512.
    const size_t fbase = ((size_t)(mb * 2) * 64 + q) * 512 + quad * 128 + l16 * 8;

    // Producer epilogue geometry: 4 contiguous 1-KB runs (mt x kw-local).
    const int r_   = tid >> 7;            // run 0..3
    const int pos  = (tid & 127) * 4;     // halfs within run
    const int mt_w = r_ >> 1, kwl = r_ & 1;
    const int l16w = (pos >> 3) & 15, qw = pos >> 7, jw = pos & 7;
    const int m_loc = mt_w * 16 + l16w;                 // m within band
    const int nn    = kwl * 32 + qw * 8 + jw;           // n within block (0..63)
    const size_t soff = ((size_t)(mb * 2 + mt_w) * 64 + (nb * 2 + kwl)) * 512 + pos;

    unsigned fastw = 0;   // wave0's register copy of the fast-path predicate

    #pragma unroll 1
    for (int t = 0; t < kT; ++t) {
        // ---- X-frag raw loads for THIS step (latency hidden under sync) ----
        float4 xr[2][2];
        if (q < 2) {
            #pragma unroll
            for (int i = 0; i < 2; ++i) {
                const float* xp = X + ((size_t)(m0 + i * 16 + l16) * kT + t) * kIN
                                + q * 32 + quad * 8;
                xr[i][0] = *(const float4*)xp;
                xr[i][1] = *(const float4*)(xp + 4);
            }
        }

        f32x4 acc[2][2] = {};   // [m-tile][n-tile within n-half]

        // ---- recurrent term: direct swizzled fragment loads, 4x8 pipeline ----
        if (t > 0) {
            const _Float16* sprev = (t & 1) ? sbuf0 : sbuf1;
            const unsigned target = (unsigned)t;   // flag >= t <=> s[t-1] published

            if (wave == 0) {
                // whole-band detect (steady state: all published together)
                unsigned fm = poll32(bandflags, lane, target);
                while (fm != 0xffffffffu) {
                    __builtin_amdgcn_s_sleep(1);
                    fm = poll32(bandflags, lane, target);
                }
                if (t == 1) {
                    // one-time: verify XCD co-location (xcds visible: flag>=1)
                    const unsigned myx = get_xcc_id() + 1u;
                    unsigned px = __hip_atomic_load(bandxcc + (lane & 31),
                                                    __ATOMIC_RELAXED,
                                                    __HIP_MEMORY_SCOPE_AGENT);
                    fastw = (__ballot(px == myx) == ~0ull) ? 1u : 0u;
                    if (lane == 0) fast_sh = (int)fastw;
                }
                if (fastw && t >= 2) {
                    // fast: L1-only invalidate (per-CU, parallel); s lives in
                    // this XCD's shared L2, updated directly by peers' stores.
                    asm volatile("buffer_inv sc0" ::: "memory");
                } else {
                    // safe: full agent acquire (L1+L2 invalidate)
                    __builtin_amdgcn_fence(__ATOMIC_ACQUIRE, "agent");
                }
            }
            __syncthreads();                       // barrier 1 (detect/inv)
            asm volatile("" ::: "memory");

            const _Float16* fp = sprev + fbase;
            f16x8 afb[2][8];   // double-buffered fragment groups (4j x 2mt)

            // group 0
            #pragma unroll
            for (int jj = 0; jj < 4; ++jj)
                #pragma unroll
                for (int i = 0; i < 2; ++i)
                    afb[0][jj * 2 + i] = *(const f16x8*)(fp + (size_t)i * 32768
                                                         + (size_t)jj * 2048);
            #pragma unroll
            for (int g = 0; g < 4; ++g) {
                if (g + 1 < 4) {   // issue next group while computing this one
                    #pragma unroll
                    for (int jj = 0; jj < 4; ++jj)
                        #pragma unroll
                        for (int i = 0; i < 2; ++i)
                            afb[(g + 1) & 1][jj * 2 + i] =
                                *(const f16x8*)(fp + (size_t)i * 32768
                                                + (size_t)((g + 1) * 4 + jj) * 2048);
                }
                #pragma unroll
                for (int jj = 0; jj < 4; ++jj) {
                    const int j = g * 4 + jj;
                    #pragma unroll
                    for (int i = 0; i < 2; ++i) {
                        f16x8 av = afb[g & 1][jj * 2 + i];
                        acc[i][0] = MFMA16(av, wfrag[0][j], acc[i][0]);
                        acc[i][1] = MFMA16(av, wfrag[1][j], acc[i][1]);
                    }
                }
            }
        }

        // ---- input term (X loads long done) ----
        if (q < 2) {
            #pragma unroll
            for (int i = 0; i < 2; ++i) {
                f16x8 a = cvt8(xr[i][0], xr[i][1]);
                acc[i][0] = MFMA16(a, winfrag[0], acc[i][0]);
                acc[i][1] = MFMA16(a, winfrag[1], acc[i][1]);
            }
        }

        // ---- reduce 4 k-phase partials through LDS, tanh, swizzled store ----
        #pragma unroll
        for (int i = 0; i < 2; ++i)
            #pragma unroll
            for (int h = 0; h < 2; ++h)
                #pragma unroll
                for (int r = 0; r < 4; ++r)
                    pf[q * BM * PFS + (i * 16 + quad * 4 + r) * PFS + nh * 32 + h * 16 + l16]
                        = acc[i][h][r];
        __syncthreads();                           // barrier 2 (pf)

        f32x4 v0 = *(const f32x4*)&pf[0 * BM * PFS + m_loc * PFS + nn];
        f32x4 v1 = *(const f32x4*)&pf[1 * BM * PFS + m_loc * PFS + nn];
        f32x4 v2 = *(const f32x4*)&pf[2 * BM * PFS + m_loc * PFS + nn];
        f32x4 v3 = *(const f32x4*)&pf[3 * BM * PFS + m_loc * PFS + nn];
        float o0 = tanhf(v0[0] + v1[0] + v2[0] + v3[0]);
        float o1 = tanhf(v0[1] + v1[1] + v2[1] + v3[1]);
        float o2 = tanhf(v0[2] + v1[2] + v2[2] + v3[2]);
        float o3 = tanhf(v0[3] + v1[3] + v2[3] + v3[3]);

        if (t < kT - 1) {
            _Float16* sout = (t & 1) ? sbuf1 : sbuf0;
            union { u64 u; _Float16 h[4]; } pk;
            pk.h[0] = (_Float16)o0; pk.h[1] = (_Float16)o1;
            pk.h[2] = (_Float16)o2; pk.h[3] = (_Float16)o3;
            u64* dst = (u64*)(sout + soff);        // contiguous across tids
            if (fast_sh) {
                *dst = pk.u;                     // write-back: lands in the
                asm volatile("" ::: "memory");   // XCD's shared L2 (verified)
            } else {
                __hip_atomic_store(dst, pk.u, __ATOMIC_RELAXED,
                                   __HIP_MEMORY_SCOPE_AGENT);  // through to L3
            }
            __builtin_amdgcn_s_waitcnt(0);   // store (and xcc publish) completed
            __syncthreads();                 // barrier 3 (drain; guards pf)
            if (tid == 0)
                __hip_atomic_store(&bandflags[nb], (unsigned)(t + 1),
                                   __ATOMIC_RELAXED, __HIP_MEMORY_SCOPE_AGENT);
        } else {
            // final step: write plain [B, R] fp32 output
            float4 o; o.x = o0; o.y = o1; o.z = o2; o.w = o3;
            *(float4*)(out + (size_t)(m0 + m_loc) * kR + n0 + nn) = o;
        }
    }
}

extern "C" void kernel_launch(void* const* d_in, const int* in_sizes, int n_in,
                              void* d_out, int out_size, void* d_ws, size_t ws_size,
                              hipStream_t stream)
{
    const float* X   = (const float*)d_in[0];  // [B, T, IN]
    const float* Win = (const float*)d_in[1];  // [R, IN]
    const float* W   = (const float*)d_in[2];  // [R, R]
    float* out = (float*)d_out;                // [B, R]

    char* ws = (char*)d_ws;
    _Float16* s0 = (_Float16*)ws;                                  // 1 MB (swizzled)
    _Float16* s1 = (_Float16*)(ws + (size_t)kB * kR * 2);          // 1 MB (swizzled)
    unsigned* flags = (unsigned*)(ws + 2 * (size_t)kB * kR * 2);   // [8][32]
    unsigned* xcds  = flags + kBands * kNB;                        // [8][32]

    hipMemsetAsync(flags, 0, 2 * kBands * kNB * sizeof(unsigned), stream);
    esn_persist<<<kBlocks, 512, 0, stream>>>(X, Win, W, out, s0, s1, flags, xcds);
}

// Round 16
// 1963.321 us; speedup vs baseline: 1.3097x; 1.1085x over previous
//
#include <hip/hip_runtime.h>
#include <hip/hip_fp16.h>
#include <cmath>

// Problem constants (reference: B=256, T=512, IN=64, R=2048)
constexpr int kB  = 256;
constexpr int kT  = 512;
constexpr int kIN = 64;
constexpr int kR  = 2048;

constexpr int kBands  = 8;             // m-bands; band = blockIdx&7 -> XCD-local under
                                       // round-robin dispatch (r9/r12-verified)
constexpr int kNB     = 32;            // n-blocks per band
constexpr int kBlocks = kBands * kNB;  // 256 -> 1 block/CU (r10: 2/CU regresses)
constexpr int BM = 32;                 // batches per block
constexpr int BN = 64;                 // n per block (W-band in registers)
constexpr int PFS = 68;                // partial-scratch row stride (words)

typedef _Float16 f16x8 __attribute__((ext_vector_type(8)));
typedef float    f32x4 __attribute__((ext_vector_type(4)));
typedef unsigned long long u64;

#define MFMA16(a, b, c) __builtin_amdgcn_mfma_f32_16x16x32_f16((a), (b), (c), 0, 0, 0)

__device__ __forceinline__ f16x8 cvt8(float4 a, float4 b) {
    f16x8 v;
    v[0] = (_Float16)a.x; v[1] = (_Float16)a.y; v[2] = (_Float16)a.z; v[3] = (_Float16)a.w;
    v[4] = (_Float16)b.x; v[5] = (_Float16)b.y; v[6] = (_Float16)b.z; v[7] = (_Float16)b.w;
    return v;
}

__device__ __forceinline__ unsigned get_xcc_id() {
    unsigned x;
    asm volatile("s_getreg_b32 %0, hwreg(HW_REG_XCC_ID, 0, 8)" : "=s"(x));
    return x & 0xfu;
}

// One coalesced poll of the band's 32 per-block flags (agent-scope).
__device__ __forceinline__ unsigned poll32(const unsigned* f, int lane, unsigned target) {
    unsigned v = __hip_atomic_load(f + (lane & 31), __ATOMIC_RELAXED, __HIP_MEMORY_SCOPE_AGENT);
    return (unsigned)__ballot(v >= target);
}

// Persistent ESN, r16 = r15 (swizzled fragment exchange, 2.18 ms) with an
// 8-way k-phase wave split (q = 0..7, no n-half): each wave owns a disjoint
// 256-k slab x all 64 n, so the 8 waves' fragment loads are fully DISJOINT —
// block L2 read traffic halves to the 128 KB/step minimum (r15's (nh,q) split
// read every fragment twice, and the per-step L1 inv defeats L1 dedup).
// Cost: partial reduce widens 4 -> 8 phases (pf 70 KB). Coherence (r12
// verified XCD fast path), swizzled layout, epilogue geometry: unchanged.
__global__ __launch_bounds__(512, 2) void esn_persist(
    const float* __restrict__ X,     // [B, T, IN]
    const float* __restrict__ Win,   // [R, IN]
    const float* __restrict__ W,     // [R, R]
    float* __restrict__ out,         // [B, R]
    _Float16* __restrict__ sbuf0,    // swizzled, 1 MB
    _Float16* __restrict__ sbuf1,    // swizzled, 1 MB
    unsigned* __restrict__ flags,    // [8][32], zeroed at launch
    unsigned* __restrict__ xcds)     // [8][32], zeroed at launch
{
    __shared__ __align__(16) float pf[8 * BM * PFS];     // 69632 B
    __shared__ int fast_sh;

    const int tid  = threadIdx.x;
    const int wave = tid >> 6, lane = tid & 63;
    const int quad = lane >> 4, l16 = lane & 15;
    const int q  = wave;             // k-phase: k-slab [256q, 256q+256)
    const int mb = blockIdx.x & 7;   // band (XCD-local heuristic, HW-verified)
    const int nb = blockIdx.x >> 3;  // n-block within band
    const int n0 = nb * BN;
    const int m0 = mb * BM;
    unsigned* bandflags = flags + mb * kNB;
    unsigned* bandxcc   = xcds  + mb * kNB;

    if (tid == 0) {
        fast_sh = 0;
        __hip_atomic_store(&bandxcc[nb], get_xcc_id() + 1u,
                           __ATOMIC_RELAXED, __HIP_MEMORY_SCOPE_AGENT);
    }

    // ---- one-time: W-band -> register B-frags (f16) ----
    // wfrag[nt][j] = W[n0+nt*16+l16][kk*32+quad*8+..], kk = 8q+j, j=0..7
    f16x8 wfrag[4][8];
    #pragma unroll
    for (int nt = 0; nt < 4; ++nt) {
        const float* wrow = W + (size_t)(n0 + nt * 16 + l16) * kR;
        #pragma unroll
        for (int j = 0; j < 8; ++j) {
            const float* p = wrow + (8 * q + j) * 32 + quad * 8;
            wfrag[nt][j] = cvt8(*(const float4*)p, *(const float4*)(p + 4));
        }
    }
    // input term: K=64 = 2 k-windows; waves q=0,1 own window q
    f16x8 winfrag[4] = {};
    if (q < 2) {
        #pragma unroll
        for (int nt = 0; nt < 4; ++nt) {
            const float* p = Win + (size_t)(n0 + nt * 16 + l16) * kIN
                           + q * 32 + quad * 8;
            winfrag[nt] = cvt8(*(const float4*)p, *(const float4*)(p + 4));
        }
    }

    // Consumer fragment geometry (swizzled layout, r15-verified):
    // frag (mt, j) at halfs offset fbase + mt*32768 + j*512, kw = 8q+j.
    const size_t fbase = ((size_t)(mb * 2) * 64 + 8 * q) * 512 + quad * 128 + l16 * 8;

    // Producer epilogue geometry (r15-verified): 4 contiguous 1-KB runs.
    const int r_   = tid >> 7;            // run 0..3
    const int pos  = (tid & 127) * 4;     // halfs within run
    const int mt_w = r_ >> 1, kwl = r_ & 1;
    const int l16w = (pos >> 3) & 15, qw = pos >> 7, jw = pos & 7;
    const int m_loc = mt_w * 16 + l16w;                 // m within band
    const int nn    = kwl * 32 + qw * 8 + jw;           // n within block (0..63)
    const size_t soff = ((size_t)(mb * 2 + mt_w) * 64 + (nb * 2 + kwl)) * 512 + pos;

    unsigned fastw = 0;   // wave0's register copy of the fast-path predicate

    #pragma unroll 1
    for (int t = 0; t < kT; ++t) {
        // ---- X-frag raw loads for THIS step (latency hidden under sync) ----
        float4 xr[2][2];
        if (q < 2) {
            #pragma unroll
            for (int i = 0; i < 2; ++i) {
                const float* xp = X + ((size_t)(m0 + i * 16 + l16) * kT + t) * kIN
                                + q * 32 + quad * 8;
                xr[i][0] = *(const float4*)xp;
                xr[i][1] = *(const float4*)(xp + 4);
            }
        }

        f32x4 acc[2][4] = {};   // [m-tile][n-tile]

        // ---- recurrent term: disjoint swizzled fragment loads, 2x8 dbuf ----
        if (t > 0) {
            const _Float16* sprev = (t & 1) ? sbuf0 : sbuf1;
            const unsigned target = (unsigned)t;   // flag >= t <=> s[t-1] published

            if (wave == 0) {
                // whole-band detect (steady state: all published together)
                unsigned fm = poll32(bandflags, lane, target);
                while (fm != 0xffffffffu) {
                    __builtin_amdgcn_s_sleep(1);
                    fm = poll32(bandflags, lane, target);
                }
                if (t == 1) {
                    // one-time: verify XCD co-location (xcds visible: flag>=1)
                    const unsigned myx = get_xcc_id() + 1u;
                    unsigned px = __hip_atomic_load(bandxcc + (lane & 31),
                                                    __ATOMIC_RELAXED,
                                                    __HIP_MEMORY_SCOPE_AGENT);
                    fastw = (__ballot(px == myx) == ~0ull) ? 1u : 0u;
                    if (lane == 0) fast_sh = (int)fastw;
                }
                if (fastw && t >= 2) {
                    // fast: L1-only invalidate (per-CU, parallel); s lives in
                    // this XCD's shared L2, updated directly by peers' stores.
                    asm volatile("buffer_inv sc0" ::: "memory");
                } else {
                    // safe: full agent acquire (L1+L2 invalidate)
                    __builtin_amdgcn_fence(__ATOMIC_ACQUIRE, "agent");
                }
            }
            __syncthreads();                       // barrier 1 (detect/inv)
            asm volatile("" ::: "memory");

            const _Float16* fp = sprev + fbase;
            f16x8 afb[2][8];   // double-buffered groups: 4 j x 2 mt

            // group 0 (j = 0..3)
            #pragma unroll
            for (int jj = 0; jj < 4; ++jj)
                #pragma unroll
                for (int i = 0; i < 2; ++i)
                    afb[0][jj * 2 + i] = *(const f16x8*)(fp + (size_t)i * 32768
                                                         + (size_t)jj * 512);
            #pragma unroll
            for (int g = 0; g < 2; ++g) {
                if (g == 0) {   // issue group 1 (j = 4..7) while computing g0
                    #pragma unroll
                    for (int jj = 0; jj < 4; ++jj)
                        #pragma unroll
                        for (int i = 0; i < 2; ++i)
                            afb[1][jj * 2 + i] =
                                *(const f16x8*)(fp + (size_t)i * 32768
                                                + (size_t)(4 + jj) * 512);
                }
                #pragma unroll
                for (int jj = 0; jj < 4; ++jj) {
                    const int j = g * 4 + jj;
                    #pragma unroll
                    for (int i = 0; i < 2; ++i) {
                        f16x8 av = afb[g][jj * 2 + i];
                        acc[i][0] = MFMA16(av, wfrag[0][j], acc[i][0]);
                        acc[i][1] = MFMA16(av, wfrag[1][j], acc[i][1]);
                        acc[i][2] = MFMA16(av, wfrag[2][j], acc[i][2]);
                        acc[i][3] = MFMA16(av, wfrag[3][j], acc[i][3]);
                    }
                }
            }
        }

        // ---- input term (X loads long done) ----
        if (q < 2) {
            #pragma unroll
            for (int i = 0; i < 2; ++i) {
                f16x8 a = cvt8(xr[i][0], xr[i][1]);
                #pragma unroll
                for (int nt = 0; nt < 4; ++nt)
                    acc[i][nt] = MFMA16(a, winfrag[nt], acc[i][nt]);
            }
        }

        // ---- reduce 8 k-phase partials through LDS, tanh, swizzled store ----
        #pragma unroll
        for (int i = 0; i < 2; ++i)
            #pragma unroll
            for (int nt = 0; nt < 4; ++nt)
                #pragma unroll
                for (int r = 0; r < 4; ++r)
                    pf[q * BM * PFS + (i * 16 + quad * 4 + r) * PFS + nt * 16 + l16]
                        = acc[i][nt][r];
        __syncthreads();                           // barrier 2 (pf)

        f32x4 vs = {};
        #pragma unroll
        for (int p = 0; p < 8; ++p) {
            f32x4 v = *(const f32x4*)&pf[p * BM * PFS + m_loc * PFS + nn];
            vs[0] += v[0]; vs[1] += v[1]; vs[2] += v[2]; vs[3] += v[3];
        }
        float o0 = tanhf(vs[0]);
        float o1 = tanhf(vs[1]);
        float o2 = tanhf(vs[2]);
        float o3 = tanhf(vs[3]);

        if (t < kT - 1) {
            _Float16* sout = (t & 1) ? sbuf1 : sbuf0;
            union { u64 u; _Float16 h[4]; } pk;
            pk.h[0] = (_Float16)o0; pk.h[1] = (_Float16)o1;
            pk.h[2] = (_Float16)o2; pk.h[3] = (_Float16)o3;
            u64* dst = (u64*)(sout + soff);        // contiguous across tids
            if (fast_sh) {
                *dst = pk.u;                     // write-back: lands in the
                asm volatile("" ::: "memory");   // XCD's shared L2 (verified)
            } else {
                __hip_atomic_store(dst, pk.u, __ATOMIC_RELAXED,
                                   __HIP_MEMORY_SCOPE_AGENT);  // through to L3
            }
            __builtin_amdgcn_s_waitcnt(0);   // store (and xcc publish) completed
            __syncthreads();                 // barrier 3 (drain; guards pf)
            if (tid == 0)
                __hip_atomic_store(&bandflags[nb], (unsigned)(t + 1),
                                   __ATOMIC_RELAXED, __HIP_MEMORY_SCOPE_AGENT);
        } else {
            // final step: write plain [B, R] fp32 output
            float4 o; o.x = o0; o.y = o1; o.z = o2; o.w = o3;
            *(float4*)(out + (size_t)(m0 + m_loc) * kR + n0 + nn) = o;
        }
    }
}

extern "C" void kernel_launch(void* const* d_in, const int* in_sizes, int n_in,
                              void* d_out, int out_size, void* d_ws, size_t ws_size,
                              hipStream_t stream)
{
    const float* X   = (const float*)d_in[0];  // [B, T, IN]
    const float* Win = (const float*)d_in[1];  // [R, IN]
    const float* W   = (const float*)d_in[2];  // [R, R]
    float* out = (float*)d_out;                // [B, R]

    char* ws = (char*)d_ws;
    _Float16* s0 = (_Float16*)ws;                                  // 1 MB (swizzled)
    _Float16* s1 = (_Float16*)(ws + (size_t)kB * kR * 2);          // 1 MB (swizzled)
    unsigned* flags = (unsigned*)(ws + 2 * (size_t)kB * kR * 2);   // [8][32]
    unsigned* xcds  = flags + kBands * kNB;                        // [8][32]

    hipMemsetAsync(flags, 0, 2 * kBands * kNB * sizeof(unsigned), stream);
    esn_persist<<<kBlocks, 512, 0, stream>>>(X, Win, W, out, s0, s1, flags, xcds);
}

// Round 17
// 1852.424 us; speedup vs baseline: 1.3881x; 1.0599x over previous
//
#include <hip/hip_runtime.h>
#include <hip/hip_fp16.h>
#include <cmath>

// Problem constants (reference: B=256, T=512, IN=64, R=2048)
constexpr int kB  = 256;
constexpr int kT  = 512;
constexpr int kIN = 64;
constexpr int kR  = 2048;

constexpr int kBands  = 8;             // m-bands; band = blockIdx&7 -> XCD-local under
                                       // round-robin dispatch (r9/r12-verified)
constexpr int kNB     = 32;            // n-blocks per band
constexpr int kBlocks = kBands * kNB;  // 256 -> 1 block/CU (r10: 2/CU regresses)
constexpr int BM = 32;                 // batches per block
constexpr int BN = 64;                 // n per block (W-band in registers)
constexpr int PFS = 68;                // partial-scratch row stride (words)

typedef _Float16 f16x8 __attribute__((ext_vector_type(8)));
typedef float    f32x4 __attribute__((ext_vector_type(4)));
typedef unsigned long long u64;

#define MFMA16(a, b, c) __builtin_amdgcn_mfma_f32_16x16x32_f16((a), (b), (c), 0, 0, 0)

__device__ __forceinline__ f16x8 cvt8(float4 a, float4 b) {
    f16x8 v;
    v[0] = (_Float16)a.x; v[1] = (_Float16)a.y; v[2] = (_Float16)a.z; v[3] = (_Float16)a.w;
    v[4] = (_Float16)b.x; v[5] = (_Float16)b.y; v[6] = (_Float16)b.z; v[7] = (_Float16)b.w;
    return v;
}

__device__ __forceinline__ unsigned get_xcc_id() {
    unsigned x;
    asm volatile("s_getreg_b32 %0, hwreg(HW_REG_XCC_ID, 0, 8)" : "=s"(x));
    return x & 0xfu;
}

// Fast tanh: 1 - 2/(e^{2x}+1) via hw v_exp_f32. Saturates exactly to +/-1 for
// large |x|; ~1e-6 abs error — negligible vs the 9.8e-3 f16-path absmax.
__device__ __forceinline__ float fast_tanh(float x) {
    float e = __expf(2.0f * x);
    return 1.0f - 2.0f / (e + 1.0f);
}

// One coalesced poll of the band's 32 per-block flags (agent-scope).
__device__ __forceinline__ unsigned poll32(const unsigned* f, int lane, unsigned target) {
    unsigned v = __hip_atomic_load(f + (lane & 31), __ATOMIC_RELAXED, __HIP_MEMORY_SCOPE_AGENT);
    return (unsigned)__ballot(v >= target);
}

// Persistent ESN, r17 = r16 (disjoint swizzled fragment exchange, 1.96 ms) +
// serial-chain trims:
//   (1) flat 16-load fragment issue (no group dbuf): all loads in flight
//       before the first MFMA — max MLP against the ~1 us/step L2 stream;
//   (2) hot-spin detect (first 16 polls sleepless — steady state resolves in
//       1-3 polls; s_sleep quantization was pure waste);
//   (3) fast tanh via v_exp_f32 (libm tanhf was ~25 VALU ops on the serial
//       epilogue path).
// Coherence (r12 verified XCD fast path), swizzled layout, 8-way k-phase
// split, epilogue geometry: unchanged.
__global__ __launch_bounds__(512, 2) void esn_persist(
    const float* __restrict__ X,     // [B, T, IN]
    const float* __restrict__ Win,   // [R, IN]
    const float* __restrict__ W,     // [R, R]
    float* __restrict__ out,         // [B, R]
    _Float16* __restrict__ sbuf0,    // swizzled, 1 MB
    _Float16* __restrict__ sbuf1,    // swizzled, 1 MB
    unsigned* __restrict__ flags,    // [8][32], zeroed at launch
    unsigned* __restrict__ xcds)     // [8][32], zeroed at launch
{
    __shared__ __align__(16) float pf[8 * BM * PFS];     // 69632 B
    __shared__ int fast_sh;

    const int tid  = threadIdx.x;
    const int wave = tid >> 6, lane = tid & 63;
    const int quad = lane >> 4, l16 = lane & 15;
    const int q  = wave;             // k-phase: k-slab [256q, 256q+256)
    const int mb = blockIdx.x & 7;   // band (XCD-local heuristic, HW-verified)
    const int nb = blockIdx.x >> 3;  // n-block within band
    const int n0 = nb * BN;
    const int m0 = mb * BM;
    unsigned* bandflags = flags + mb * kNB;
    unsigned* bandxcc   = xcds  + mb * kNB;

    if (tid == 0) {
        fast_sh = 0;
        __hip_atomic_store(&bandxcc[nb], get_xcc_id() + 1u,
                           __ATOMIC_RELAXED, __HIP_MEMORY_SCOPE_AGENT);
    }

    // ---- one-time: W-band -> register B-frags (f16) ----
    // wfrag[nt][j] = W[n0+nt*16+l16][kk*32+quad*8+..], kk = 8q+j, j=0..7
    f16x8 wfrag[4][8];
    #pragma unroll
    for (int nt = 0; nt < 4; ++nt) {
        const float* wrow = W + (size_t)(n0 + nt * 16 + l16) * kR;
        #pragma unroll
        for (int j = 0; j < 8; ++j) {
            const float* p = wrow + (8 * q + j) * 32 + quad * 8;
            wfrag[nt][j] = cvt8(*(const float4*)p, *(const float4*)(p + 4));
        }
    }
    // input term: K=64 = 2 k-windows; waves q=0,1 own window q
    f16x8 winfrag[4] = {};
    if (q < 2) {
        #pragma unroll
        for (int nt = 0; nt < 4; ++nt) {
            const float* p = Win + (size_t)(n0 + nt * 16 + l16) * kIN
                           + q * 32 + quad * 8;
            winfrag[nt] = cvt8(*(const float4*)p, *(const float4*)(p + 4));
        }
    }

    // Consumer fragment geometry (swizzled layout, r15-verified):
    // frag (mt, j) at halfs offset fbase + mt*32768 + j*512, kw = 8q+j.
    const size_t fbase = ((size_t)(mb * 2) * 64 + 8 * q) * 512 + quad * 128 + l16 * 8;

    // Producer epilogue geometry (r15-verified): 4 contiguous 1-KB runs.
    const int r_   = tid >> 7;            // run 0..3
    const int pos  = (tid & 127) * 4;     // halfs within run
    const int mt_w = r_ >> 1, kwl = r_ & 1;
    const int l16w = (pos >> 3) & 15, qw = pos >> 7, jw = pos & 7;
    const int m_loc = mt_w * 16 + l16w;                 // m within band
    const int nn    = kwl * 32 + qw * 8 + jw;           // n within block (0..63)
    const size_t soff = ((size_t)(mb * 2 + mt_w) * 64 + (nb * 2 + kwl)) * 512 + pos;

    unsigned fastw = 0;   // wave0's register copy of the fast-path predicate

    #pragma unroll 1
    for (int t = 0; t < kT; ++t) {
        // ---- X-frag raw loads for THIS step (latency hidden under sync) ----
        float4 xr[2][2];
        if (q < 2) {
            #pragma unroll
            for (int i = 0; i < 2; ++i) {
                const float* xp = X + ((size_t)(m0 + i * 16 + l16) * kT + t) * kIN
                                + q * 32 + quad * 8;
                xr[i][0] = *(const float4*)xp;
                xr[i][1] = *(const float4*)(xp + 4);
            }
        }

        f32x4 acc[2][4] = {};   // [m-tile][n-tile]

        // ---- recurrent term: disjoint swizzled fragment loads, flat issue ----
        if (t > 0) {
            const _Float16* sprev = (t & 1) ? sbuf0 : sbuf1;
            const unsigned target = (unsigned)t;   // flag >= t <=> s[t-1] published

            if (wave == 0) {
                // whole-band detect; hot-spin first, sleep only if straggling
                unsigned fm = poll32(bandflags, lane, target);
                int spins = 0;
                while (fm != 0xffffffffu) {
                    if (++spins > 16) __builtin_amdgcn_s_sleep(1);
                    fm = poll32(bandflags, lane, target);
                }
                if (t == 1) {
                    // one-time: verify XCD co-location (xcds visible: flag>=1)
                    const unsigned myx = get_xcc_id() + 1u;
                    unsigned px = __hip_atomic_load(bandxcc + (lane & 31),
                                                    __ATOMIC_RELAXED,
                                                    __HIP_MEMORY_SCOPE_AGENT);
                    fastw = (__ballot(px == myx) == ~0ull) ? 1u : 0u;
                    if (lane == 0) fast_sh = (int)fastw;
                }
                if (fastw && t >= 2) {
                    // fast: L1-only invalidate (per-CU, parallel); s lives in
                    // this XCD's shared L2, updated directly by peers' stores.
                    asm volatile("buffer_inv sc0" ::: "memory");
                } else {
                    // safe: full agent acquire (L1+L2 invalidate)
                    __builtin_amdgcn_fence(__ATOMIC_ACQUIRE, "agent");
                }
            }
            __syncthreads();                       // barrier 1 (detect/inv)
            asm volatile("" ::: "memory");

            const _Float16* fp = sprev + fbase;
            f16x8 af[16];   // all 16 fragments: flat issue, max MLP

            #pragma unroll
            for (int j = 0; j < 8; ++j)
                #pragma unroll
                for (int i = 0; i < 2; ++i)
                    af[j * 2 + i] = *(const f16x8*)(fp + (size_t)i * 32768
                                                    + (size_t)j * 512);
            #pragma unroll
            for (int j = 0; j < 8; ++j) {
                #pragma unroll
                for (int i = 0; i < 2; ++i) {
                    f16x8 av = af[j * 2 + i];
                    acc[i][0] = MFMA16(av, wfrag[0][j], acc[i][0]);
                    acc[i][1] = MFMA16(av, wfrag[1][j], acc[i][1]);
                    acc[i][2] = MFMA16(av, wfrag[2][j], acc[i][2]);
                    acc[i][3] = MFMA16(av, wfrag[3][j], acc[i][3]);
                }
            }
        }

        // ---- input term (X loads long done) ----
        if (q < 2) {
            #pragma unroll
            for (int i = 0; i < 2; ++i) {
                f16x8 a = cvt8(xr[i][0], xr[i][1]);
                #pragma unroll
                for (int nt = 0; nt < 4; ++nt)
                    acc[i][nt] = MFMA16(a, winfrag[nt], acc[i][nt]);
            }
        }

        // ---- reduce 8 k-phase partials through LDS, tanh, swizzled store ----
        #pragma unroll
        for (int i = 0; i < 2; ++i)
            #pragma unroll
            for (int nt = 0; nt < 4; ++nt)
                #pragma unroll
                for (int r = 0; r < 4; ++r)
                    pf[q * BM * PFS + (i * 16 + quad * 4 + r) * PFS + nt * 16 + l16]
                        = acc[i][nt][r];
        __syncthreads();                           // barrier 2 (pf)

        f32x4 vs = {};
        #pragma unroll
        for (int p = 0; p < 8; ++p) {
            f32x4 v = *(const f32x4*)&pf[p * BM * PFS + m_loc * PFS + nn];
            vs[0] += v[0]; vs[1] += v[1]; vs[2] += v[2]; vs[3] += v[3];
        }
        float o0 = fast_tanh(vs[0]);
        float o1 = fast_tanh(vs[1]);
        float o2 = fast_tanh(vs[2]);
        float o3 = fast_tanh(vs[3]);

        if (t < kT - 1) {
            _Float16* sout = (t & 1) ? sbuf1 : sbuf0;
            union { u64 u; _Float16 h[4]; } pk;
            pk.h[0] = (_Float16)o0; pk.h[1] = (_Float16)o1;
            pk.h[2] = (_Float16)o2; pk.h[3] = (_Float16)o3;
            u64* dst = (u64*)(sout + soff);        // contiguous across tids
            if (fast_sh) {
                *dst = pk.u;                     // write-back: lands in the
                asm volatile("" ::: "memory");   // XCD's shared L2 (verified)
            } else {
                __hip_atomic_store(dst, pk.u, __ATOMIC_RELAXED,
                                   __HIP_MEMORY_SCOPE_AGENT);  // through to L3
            }
            __builtin_amdgcn_s_waitcnt(0);   // store (and xcc publish) completed
            __syncthreads();                 // barrier 3 (drain; guards pf)
            if (tid == 0)
                __hip_atomic_store(&bandflags[nb], (unsigned)(t + 1),
                                   __ATOMIC_RELAXED, __HIP_MEMORY_SCOPE_AGENT);
        } else {
            // final step: write plain [B, R] fp32 output
            float4 o; o.x = o0; o.y = o1; o.z = o2; o.w = o3;
            *(float4*)(out + (size_t)(m0 + m_loc) * kR + n0 + nn) = o;
        }
    }
}

extern "C" void kernel_launch(void* const* d_in, const int* in_sizes, int n_in,
                              void* d_out, int out_size, void* d_ws, size_t ws_size,
                              hipStream_t stream)
{
    const float* X   = (const float*)d_in[0];  // [B, T, IN]
    const float* Win = (const float*)d_in[1];  // [R, IN]
    const float* W   = (const float*)d_in[2];  // [R, R]
    float* out = (float*)d_out;                // [B, R]

    char* ws = (char*)d_ws;
    _Float16* s0 = (_Float16*)ws;                                  // 1 MB (swizzled)
    _Float16* s1 = (_Float16*)(ws + (size_t)kB * kR * 2);          // 1 MB (swizzled)
    unsigned* flags = (unsigned*)(ws + 2 * (size_t)kB * kR * 2);   // [8][32]
    unsigned* xcds  = flags + kBands * kNB;                        // [8][32]

    hipMemsetAsync(flags, 0, 2 * kBands * kNB * sizeof(unsigned), stream);
    esn_persist<<<kBlocks, 512, 0, stream>>>(X, Win, W, out, s0, s1, flags, xcds);
}